// Round 1
// baseline (34746.893 us; speedup 1.0000x reference)
//
#include <hip/hip_runtime.h>
#include <hip/hip_bf16.h>

#define B 128
#define T 1024

// ---------------- helpers ----------------
__device__ __forceinline__ float sigm(float x){ return 1.f/(1.f+__expf(-x)); }
__device__ __forceinline__ float tanh_(float x){ return 1.f - 2.f/(1.f+__expf(2.f*x)); }
__device__ __forceinline__ unsigned short f2b(float f){
  unsigned u = __float_as_uint(f);
  u += 0x7FFFu + ((u>>16)&1u);
  return (unsigned short)(u>>16);
}
__device__ __forceinline__ float b2f(unsigned short s){ return __uint_as_float(((unsigned)s)<<16); }
__device__ __forceinline__ void stG(float* p, float v){ __hip_atomic_store(p, v, __ATOMIC_RELAXED, __HIP_MEMORY_SCOPE_AGENT); }
__device__ __forceinline__ float ldG(const float* p){ return __hip_atomic_load(p, __ATOMIC_RELAXED, __HIP_MEMORY_SCOPE_AGENT); }
__device__ __forceinline__ void fma4(float4& a, float s, const float4& v){
  a.x += s*v.x; a.y += s*v.y; a.z += s*v.z; a.w += s*v.w;
}

// ---------------- static device buffers (no d_ws dependence) ----------------
__device__ float g_hg1[2*16*8*304];                 // layer1 h exchange, ping-pong
__device__ float g_hg2[2*16*8*256];                 // layer2 h exchange
__device__ unsigned short g_h1[(size_t)B*T*304];    // layer1 output, bf16, padded to 304
__device__ unsigned short g_xp3[(size_t)B*T*256];   // input projection for layer3, bf16
__device__ float4 g_xp4[(size_t)B*T];               // input projection for layer4, fp32
__device__ int g_ctrl[2*16*32];                     // barrier counters, 128B-strided

__global__ void k_zero_ctrl(){
  int i = threadIdx.x;
  if (i < 2*16*32) g_ctrl[i] = 0;
}

// monotonic-counter cluster barrier: tid0 release-arrives, acquire-spins
__device__ __forceinline__ void cluster_barrier(int* cnt, int target){
  if (threadIdx.x == 0){
    __hip_atomic_fetch_add(cnt, 1, __ATOMIC_RELEASE, __HIP_MEMORY_SCOPE_AGENT);
    while (__hip_atomic_load(cnt, __ATOMIC_ACQUIRE, __HIP_MEMORY_SCOPE_AGENT) < target)
      __builtin_amdgcn_s_sleep(1);
  }
  __syncthreads();
}

// ============== Layer 1: H=300, Din=1 folded. 16 clusters x 15 WGs, Bs=8 ==============
// WG owns 20 hidden units (80 gate rows). K = 301 padded to 304 (k==300 is the x column).
__global__ __launch_bounds__(320) void k_l1(const float* __restrict__ x,
    const float* __restrict__ wih, const float* __restrict__ whh,
    const float* __restrict__ bih, const float* __restrict__ bhh){
  __shared__ float4 sW[304*21];   // [k][row-quad(20)+pad] quad = 4 rows at same k
  __shared__ float4 sV[304*2];    // [k][batch-quad(2)]
  __shared__ float  sP[80*8*9];   // partials [row][b][ks(8)+pad]
  __shared__ float  sBsum[80];
  __shared__ float  sC[20*8];     // c state [u][b]
  const int tid = threadIdx.x;
  const int cl = blockIdx.x / 15, wg = blockIdx.x % 15;
  const int b0 = cl*8, u0 = wg*20;
  float* sWf = (float*)sW; float* sVf = (float*)sV;

  for (int idx=tid; idx<80*304; idx+=320){
    int lr = idx/304, k = idx - lr*304;
    int g = lr/20, ul = lr - g*20;
    int grow = g*300 + u0 + ul;
    float w = 0.f;
    if (k < 300) w = whh[grow*300 + k];
    else if (k == 300) w = wih[grow];
    sWf[(k*21 + (lr>>2))*4 + (lr&3)] = w;
  }
  for (int idx=tid; idx<80; idx+=320){
    int g = idx/20, ul = idx - g*20; int grow = g*300 + u0 + ul;
    sBsum[idx] = bih[grow] + bhh[grow];
  }
  for (int idx=tid; idx<160; idx+=320) sC[idx] = 0.f;
  for (int idx=tid; idx<304*8; idx+=320){           // v for t=0: h=0, x at k==300
    int k = idx>>3, b = idx&7;
    float v = (k==300) ? x[(b0+b)*T + 0] : 0.f;
    sVf[(k*2 + (b>>2))*4 + (b&3)] = v;
  }
  __syncthreads();

  const int rq = tid>>4, bg = (tid>>3)&1, ks = tid&7;   // rq:0..19, bg:0..1, ks:0..7
  int* cnt = &g_ctrl[(0*16 + cl)*32];
  for (int t=0; t<T; ++t){
    // ---- partial matvec: 4 rows x 4 batch per thread, 38 k each ----
    float4 a0={0,0,0,0}, a1=a0, a2=a0, a3=a0;
    {
      const float4* wp = &sW[(ks*38)*21 + rq];
      const float4* vp = &sV[(ks*38)*2 + bg];
      #pragma unroll 2
      for (int k=0; k<38; ++k){
        float4 wq = wp[k*21]; float4 vq = vp[k*2];
        fma4(a0, wq.x, vq); fma4(a1, wq.y, vq); fma4(a2, wq.z, vq); fma4(a3, wq.w, vq);
      }
    }
    {
      int lrb = rq*4, bb = bg*4;
      float4 as[4] = {a0,a1,a2,a3};
      #pragma unroll
      for (int j=0;j<4;++j){
        sP[((lrb+j)*8+bb+0)*9+ks]=as[j].x; sP[((lrb+j)*8+bb+1)*9+ks]=as[j].y;
        sP[((lrb+j)*8+bb+2)*9+ks]=as[j].z; sP[((lrb+j)*8+bb+3)*9+ks]=as[j].w;
      }
    }
    __syncthreads();
    // ---- finalize: 20 units x 8 batch ----
    if (tid < 160){
      int u = tid % 20, b = tid / 20;
      float gs[4];
      #pragma unroll
      for (int g=0; g<4; ++g){
        int base = ((g*20+u)*8 + b)*9;
        float s = sBsum[g*20+u];
        #pragma unroll
        for (int q=0;q<8;++q) s += sP[base+q];
        gs[g] = s;
      }
      float c = sigm(gs[1])*sC[u*8+b] + sigm(gs[0])*tanh_(gs[2]);
      sC[u*8+b] = c;
      float h = sigm(gs[3])*tanh_(c);
      stG(&g_hg1[(((t&1)*16 + cl)*8 + b)*304 + u0 + u], h);
      g_h1[(size_t)((b0+b)*T + t)*304 + u0 + u] = f2b(h);
    }
    __syncthreads();
    cluster_barrier(cnt, (t+1)*15);
    // ---- stage v for t+1 ----
    for (int idx=tid; idx<304*8; idx+=320){
      int k = idx>>3, b = idx&7;
      float v;
      if (k < 300)      v = ldG(&g_hg1[(((t&1)*16 + cl)*8 + b)*304 + k]);
      else if (k == 300) v = (t+1<T) ? x[(b0+b)*T + t+1] : 0.f;
      else              v = 0.f;
      sVf[(k*2 + (b>>2))*4 + (b&3)] = v;
    }
    __syncthreads();
  }
}

// ============== Layer 2: H=256, Din=300 (bf16 W_ih folded). 16 clusters x 16 WGs ==============
// Also produces xp3 (= w_ih3 @ h2) per step.
__global__ __launch_bounds__(256) void k_l2(
    const float* __restrict__ wih, const float* __restrict__ whh,
    const float* __restrict__ bih, const float* __restrict__ bhh,
    const float* __restrict__ wih3){
  __shared__ float4  sWh[256*17];
  __shared__ ushort4 sWx[304*17];
  __shared__ float4  sVh[256*2];
  __shared__ float4  sVx[304*2];
  __shared__ float   sP[64*8*9];
  __shared__ float   sBsum[64];
  __shared__ float   sC[16*8];
  const int tid = threadIdx.x;
  const int cl = blockIdx.x >> 4, wg = blockIdx.x & 15;
  const int b0 = cl*8, u0 = wg*16;
  float* sWhf=(float*)sWh; unsigned short* sWxu=(unsigned short*)sWx;
  float* sVhf=(float*)sVh; float* sVxf=(float*)sVx;

  for (int idx=tid; idx<64*256; idx+=256){
    int lr = idx>>8, k = idx&255;
    int g = lr>>4, ul = lr&15; int grow = g*256 + u0 + ul;
    sWhf[(k*17 + (lr>>2))*4 + (lr&3)] = whh[grow*256 + k];
  }
  for (int idx=tid; idx<64*304; idx+=256){
    int lr = idx/304, k = idx - lr*304;
    int g = lr>>4, ul = lr&15; int grow = g*256 + u0 + ul;
    float w = (k<300) ? wih[grow*300 + k] : 0.f;
    sWxu[(k*17 + (lr>>2))*4 + (lr&3)] = f2b(w);
  }
  for (int idx=tid; idx<64; idx+=256){
    int g = idx>>4, ul = idx&15; int grow = g*256 + u0 + ul;
    sBsum[idx] = bih[grow] + bhh[grow];
  }
  for (int idx=tid; idx<128; idx+=256) sC[idx] = 0.f;
  for (int idx=tid; idx<256*8; idx+=256){ int k=idx>>3, b=idx&7; sVhf[(k*2+(b>>2))*4+(b&3)] = 0.f; }
  for (int idx=tid; idx<304*8; idx+=256){
    int k=idx>>3, b=idx&7;
    sVxf[(k*2+(b>>2))*4+(b&3)] = b2f(g_h1[(size_t)((b0+b)*T + 0)*304 + k]);
  }
  __syncthreads();

  const int rq = tid>>4, bg = (tid>>3)&1, ks = tid&7;
  int* cnt = &g_ctrl[(1*16 + cl)*32];
  for (int t=0; t<T; ++t){
    float4 a0={0,0,0,0}, a1=a0, a2=a0, a3=a0;
    { // recurrent part (fp32)
      const float4* wp = &sWh[(ks*32)*17 + rq];
      const float4* vp = &sVh[(ks*32)*2 + bg];
      #pragma unroll 2
      for (int k=0;k<32;++k){
        float4 wq = wp[k*17]; float4 vq = vp[k*2];
        fma4(a0,wq.x,vq); fma4(a1,wq.y,vq); fma4(a2,wq.z,vq); fma4(a3,wq.w,vq);
      }
    }
    { // input-projection part (bf16 weights)
      const ushort4* wp = &sWx[(ks*38)*17 + rq];
      const float4*  vp = &sVx[(ks*38)*2 + bg];
      #pragma unroll 2
      for (int k=0;k<38;++k){
        ushort4 uw = wp[k*17]; float4 vq = vp[k*2];
        fma4(a0,b2f(uw.x),vq); fma4(a1,b2f(uw.y),vq); fma4(a2,b2f(uw.z),vq); fma4(a3,b2f(uw.w),vq);
      }
    }
    {
      int lrb = rq*4, bb = bg*4;
      float4 as[4] = {a0,a1,a2,a3};
      #pragma unroll
      for (int j=0;j<4;++j){
        sP[((lrb+j)*8+bb+0)*9+ks]=as[j].x; sP[((lrb+j)*8+bb+1)*9+ks]=as[j].y;
        sP[((lrb+j)*8+bb+2)*9+ks]=as[j].z; sP[((lrb+j)*8+bb+3)*9+ks]=as[j].w;
      }
    }
    __syncthreads();
    if (tid < 128){
      int u = tid&15, b = tid>>4;
      float gs[4];
      #pragma unroll
      for (int g=0; g<4; ++g){
        int base = ((g*16+u)*8 + b)*9;
        float s = sBsum[g*16+u];
        #pragma unroll
        for (int q=0;q<8;++q) s += sP[base+q];
        gs[g] = s;
      }
      float c = sigm(gs[1])*sC[u*8+b] + sigm(gs[0])*tanh_(gs[2]);
      sC[u*8+b] = c;
      float h = sigm(gs[3])*tanh_(c);
      stG(&g_hg2[(((t&1)*16 + cl)*8 + b)*256 + u0 + u], h);
    }
    __syncthreads();
    cluster_barrier(cnt, (t+1)*16);
    // stage h2_t and h1[t+1]
    for (int idx=tid; idx<256*8; idx+=256){
      int k=idx>>3, b=idx&7;
      sVhf[(k*2+(b>>2))*4+(b&3)] = ldG(&g_hg2[(((t&1)*16 + cl)*8 + b)*256 + k]);
    }
    if (t+1 < T)
      for (int idx=tid; idx<304*8; idx+=256){
        int k=idx>>3, b=idx&7;
        sVxf[(k*2+(b>>2))*4+(b&3)] = b2f(g_h1[(size_t)((b0+b)*T + t+1)*304 + k]);
      }
    __syncthreads();
    // xp3[t] = w_ih3 @ h2_t for this WG's 16 rows
    {
      int g = tid&15, b = (tid>>4)&7, half = tid>>7;
      const float* wr = &wih3[(u0+g)*256 + half*128];
      float s = 0.f;
      #pragma unroll 4
      for (int k=0;k<128;k+=4){
        float4 w4 = *(const float4*)(wr + k);
        int kk = half*128 + k;
        s += w4.x*sVhf[((kk+0)*2+(b>>2))*4+(b&3)];
        s += w4.y*sVhf[((kk+1)*2+(b>>2))*4+(b&3)];
        s += w4.z*sVhf[((kk+2)*2+(b>>2))*4+(b&3)];
        s += w4.w*sVhf[((kk+3)*2+(b>>2))*4+(b&3)];
      }
      sP[(g*8+b)*2 + half] = s;
      __syncthreads();
      if (tid < 128){
        int gg = tid&15, bb = tid>>4;
        float v = sP[(gg*8+bb)*2+0] + sP[(gg*8+bb)*2+1];
        g_xp3[(size_t)((b0+bb)*T + t)*256 + u0 + gg] = f2b(v);
      }
      __syncthreads();
    }
  }
}

// ============== Layer 3 (+xp4 for layer 4): H=64, whole layer in one WG, 1 batch/WG ==============
__global__ __launch_bounds__(256) void k_l3(
    const float* __restrict__ whh, const float* __restrict__ bih,
    const float* __restrict__ bhh, const float* __restrict__ wih4){
  __shared__ float4 sW[64*65];
  __shared__ float  sV[68];
  __shared__ float  sP[256*5];
  __shared__ float  sBsum[256];
  __shared__ float  sC[64];
  __shared__ float  sW4[4*68];
  const int tid = threadIdx.x; const int b = blockIdx.x;
  float* sWf = (float*)sW;

  for (int idx=tid; idx<256*64; idx+=256){
    int lr = idx>>6, k = idx&63;
    sWf[(k*65 + (lr>>2))*4 + (lr&3)] = whh[lr*64 + k];
  }
  sBsum[tid] = bih[tid] + bhh[tid];
  if (tid < 64){ sC[tid] = 0.f; sV[tid] = 0.f; }
  if (tid < 256){ int g = tid>>6, k = tid&63; sW4[g*68+k] = wih4[g*64+k]; }
  __syncthreads();

  const int rq = tid>>2, ks = tid&3;
  for (int t=0; t<T; ++t){
    float xp[4];
    if (tid < 64){
      #pragma unroll
      for (int g=0; g<4; ++g) xp[g] = b2f(g_xp3[(size_t)(b*T + t)*256 + g*64 + tid]);
    }
    float a0=0,a1=0,a2=0,a3=0;
    const float4* wp = &sW[(ks*16)*65 + rq];
    #pragma unroll 4
    for (int k=0;k<16;++k){
      float4 wq = wp[k*65]; float v = sV[ks*16 + k];
      a0 += wq.x*v; a1 += wq.y*v; a2 += wq.z*v; a3 += wq.w*v;
    }
    int lrb = rq*4;
    sP[(lrb+0)*5+ks]=a0; sP[(lrb+1)*5+ks]=a1; sP[(lrb+2)*5+ks]=a2; sP[(lrb+3)*5+ks]=a3;
    __syncthreads();
    if (tid < 64){
      int u = tid;
      float gs[4];
      #pragma unroll
      for (int g=0;g<4;++g){
        int lr = g*64 + u;
        gs[g] = sBsum[lr] + xp[g] + sP[lr*5+0] + sP[lr*5+1] + sP[lr*5+2] + sP[lr*5+3];
      }
      float c = sigm(gs[1])*sC[u] + sigm(gs[0])*tanh_(gs[2]);
      sC[u] = c;
      sV[u] = sigm(gs[3])*tanh_(c);
    }
    __syncthreads();
    { // xp4[t] = w_ih4 @ h3_t (4 waves, one gate each)
      int g = tid>>6, k = tid&63;
      float p = sW4[g*68+k] * sV[k];
      #pragma unroll
      for (int off=32; off; off>>=1) p += __shfl_down(p, off, 64);
      if (k == 0) ((float*)&g_xp4[(size_t)b*T + t])[g] = p;
    }
  }
}

// ============== Layer 4: H=1, pure scalar scan, one thread per batch element ==============
__global__ void k_l4(const float* __restrict__ whh, const float* __restrict__ bih,
                     const float* __restrict__ bhh, float* __restrict__ out){
  int b = blockIdx.x*64 + threadIdx.x;
  float wi=whh[0], wf=whh[1], wg=whh[2], wo=whh[3];
  float bi=bih[0]+bhh[0], bf=bih[1]+bhh[1], bg=bih[2]+bhh[2], bo=bih[3]+bhh[3];
  float h=0.f, c=0.f;
  const float4* xp = &g_xp4[(size_t)b*T];
  float4 nxt = xp[0];
  for (int t=0; t<T; ++t){
    float4 cur = nxt;
    if (t+1 < T) nxt = xp[t+1];
    float ig = sigm(cur.x + wi*h + bi);
    float fg = sigm(cur.y + wf*h + bf);
    float gg = tanh_(cur.z + wg*h + bg);
    float og = sigm(cur.w + wo*h + bo);
    c = fg*c + ig*gg;
    h = og*tanh_(c);
  }
  out[b] = h;
}

extern "C" void kernel_launch(void* const* d_in, const int* in_sizes, int n_in,
                              void* d_out, int out_size, void* d_ws, size_t ws_size,
                              hipStream_t stream){
  const float* x    = (const float*)d_in[0];
  const float* wih1 = (const float*)d_in[1];
  const float* whh1 = (const float*)d_in[2];
  const float* bih1 = (const float*)d_in[3];
  const float* bhh1 = (const float*)d_in[4];
  const float* wih2 = (const float*)d_in[5];
  const float* whh2 = (const float*)d_in[6];
  const float* bih2 = (const float*)d_in[7];
  const float* bhh2 = (const float*)d_in[8];
  const float* wih3 = (const float*)d_in[9];
  const float* whh3 = (const float*)d_in[10];
  const float* bih3 = (const float*)d_in[11];
  const float* bhh3 = (const float*)d_in[12];
  const float* wih4 = (const float*)d_in[13];
  const float* whh4 = (const float*)d_in[14];
  const float* bih4 = (const float*)d_in[15];
  const float* bhh4 = (const float*)d_in[16];

  hipLaunchKernelGGL(k_zero_ctrl, dim3(1), dim3(1024), 0, stream);
  hipLaunchKernelGGL(k_l1, dim3(240), dim3(320), 0, stream, x, wih1, whh1, bih1, bhh1);
  hipLaunchKernelGGL(k_l2, dim3(256), dim3(256), 0, stream, wih2, whh2, bih2, bhh2, wih3);
  hipLaunchKernelGGL(k_l3, dim3(128), dim3(256), 0, stream, whh3, bih3, bhh3, wih4);
  hipLaunchKernelGGL(k_l4, dim3(2), dim3(64), 0, stream, whh4, bih4, bhh4, (float*)d_out);
}